// Round 1
// baseline (429.256 us; speedup 1.0000x reference)
//
#include <hip/hip_runtime.h>
#include <hip/hip_bf16.h>

#define N_NODES 50000
#define N_EDGES 800000
// encoded -inf for monotonic float->uint ordering
#define ENC_NEG_INF 0x007fffffu

__device__ __forceinline__ unsigned enc_f(float f) {
    int i = __float_as_int(f);
    return (i >= 0) ? (unsigned(i) | 0x80000000u) : ~unsigned(i);
}
__device__ __forceinline__ float dec_f(unsigned u) {
    int i = (u & 0x80000000u) ? int(u & 0x7fffffffu) : ~int(u);
    return __int_as_float(i);
}

// ---------------- k0: init accumulators ----------------
__global__ void k0_init(float* out, float* denom, unsigned* nmax) {
    long i = (long)blockIdx.x * blockDim.x + threadIdx.x;
    long total = (long)N_NODES * 64;
    for (; i < total; i += (long)gridDim.x * blockDim.x) {
        out[i] = 0.0f;
        if (i < (long)N_NODES * 4) {
            denom[i] = 0.0f;
            nmax[i] = ENC_NEG_INF;
        }
    }
}

// ---------------- k1: fused linear + attention scores ----------------
// h[n][o] = sum_k concat(x,state)[n][k] * W[o][k];  o = h*16+d
// s_src[n][h] = sum_d h[n][h][d]*attn_src[h][d]  (same for dst)
__global__ void k1_linear(const float* __restrict__ x, const float* __restrict__ state,
                          const float* __restrict__ W, const float* __restrict__ a_src,
                          const float* __restrict__ a_dst,
                          float* __restrict__ hf, float* __restrict__ s_src,
                          float* __restrict__ s_dst) {
    __shared__ float wlds[64 * 129];   // stride 129 -> (lane+k)%32 banks, conflict-free
    __shared__ float asrc_l[64];
    __shared__ float adst_l[64];
    __shared__ float inrow[4][128];    // per-wave input row

    int tid = threadIdx.x;             // 256 threads = 4 waves
    for (int i = tid; i < 64 * 128; i += 256) {
        int r = i >> 7, c = i & 127;
        wlds[r * 129 + c] = W[i];
    }
    if (tid < 64) { asrc_l[tid] = a_src[tid]; adst_l[tid] = a_dst[tid]; }
    __syncthreads();

    int wave = tid >> 6;
    int lane = tid & 63;               // output dim o
    int h = lane >> 4, d = lane & 15;
    float asv = asrc_l[lane];          // attn_src[h][d]
    float adv = adst_l[lane];
    const float* wr = &wlds[lane * 129];

    for (long n = (long)blockIdx.x * 4 + wave; n < N_NODES; n += (long)gridDim.x * 4) {
        // stage this node's 128-dim input (within-wave LDS RAW handled by lgkmcnt)
        inrow[wave][lane]      = x[n * 64 + lane];
        inrow[wave][64 + lane] = state[n * 64 + lane];
        float acc = 0.0f;
#pragma unroll 16
        for (int k = 0; k < 128; ++k)
            acc = fmaf(inrow[wave][k], wr[k], acc);
        hf[n * 64 + lane] = acc;

        float vs = acc * asv, vd = acc * adv;
#pragma unroll
        for (int off = 8; off; off >>= 1) {
            vs += __shfl_xor(vs, off);
            vd += __shfl_xor(vd, off);
        }
        if (d == 0) {
            s_src[n * 4 + h] = vs;
            s_dst[n * 4 + h] = vd;
        }
    }
}

// ---------------- k2: per-(dst,h) running max ----------------
__global__ void k2_max(const int* __restrict__ ei, const float* __restrict__ s_src,
                       const float* __restrict__ s_dst, unsigned* __restrict__ nmax) {
    int e = blockIdx.x * 256 + threadIdx.x;
    if (e >= N_EDGES) return;
    int src = ei[e];
    int dst = ei[N_EDGES + e];
    const float* ss = &s_src[(long)src * 4];
    const float* sd = &s_dst[(long)dst * 4];
#pragma unroll
    for (int h = 0; h < 4; ++h) {
        float l = ss[h] + sd[h];
        l = (l >= 0.0f) ? l : 0.2f * l;
        atomicMax(&nmax[(long)dst * 4 + h], enc_f(l));
    }
}

// ---------------- k3: exp + denom + message scatter-accumulate ----------------
// one wave per edge; lane o in [0,64)
__global__ void k3_acc(const int* __restrict__ ei, const float* __restrict__ s_src,
                       const float* __restrict__ s_dst, const unsigned* __restrict__ nmax,
                       const float* __restrict__ hf, float* __restrict__ denom,
                       float* __restrict__ out) {
    long gid = (long)blockIdx.x * blockDim.x + threadIdx.x;
    long e = gid >> 6;
    int o = (int)(gid & 63);
    if (e >= N_EDGES) return;
    int src = ei[e];
    int dst = ei[N_EDGES + e];
    int h = o >> 4;
    float l = s_src[(long)src * 4 + h] + s_dst[(long)dst * 4 + h];
    l = (l >= 0.0f) ? l : 0.2f * l;
    float ex = __expf(l - dec_f(nmax[(long)dst * 4 + h]));
    if ((o & 15) == 0) atomicAdd(&denom[(long)dst * 4 + h], ex);
    atomicAdd(&out[(long)dst * 64 + o], ex * hf[(long)src * 64 + o]);
}

// ---------------- k4: normalize + residual + ELU ----------------
__global__ void k4_fin(const float* __restrict__ hf, const float* __restrict__ denom,
                       float* __restrict__ out) {
    long i = (long)blockIdx.x * blockDim.x + threadIdx.x;
    long total = (long)N_NODES * 64;
    if (i >= total) return;
    long n = i >> 6;
    int h = (int)((i >> 4) & 3);
    float v = out[i] / (denom[n * 4 + h] + 1e-12f) + hf[i];
    out[i] = (v > 0.0f) ? v : expm1f(v);
}

extern "C" void kernel_launch(void* const* d_in, const int* in_sizes, int n_in,
                              void* d_out, int out_size, void* d_ws, size_t ws_size,
                              hipStream_t stream) {
    const float* x      = (const float*)d_in[0];
    const float* state  = (const float*)d_in[1];
    const int*   ei     = (const int*)d_in[2];     // [2, E]
    // d_in[3] = edge_weight (ignored by reference)
    const float* W      = (const float*)d_in[4];   // [64,128]
    const float* a_src  = (const float*)d_in[5];   // [4,16]
    const float* a_dst  = (const float*)d_in[6];

    float* out = (float*)d_out;                    // [N,64] also message accumulator

    // ws layout (floats): hf [N*64] | s_src [N*4] | s_dst [N*4] | denom [N*4] | nmax [N*4 uint]
    float* hf    = (float*)d_ws;
    float* s_src = hf + (long)N_NODES * 64;
    float* s_dst = s_src + (long)N_NODES * 4;
    float* denom = s_dst + (long)N_NODES * 4;
    unsigned* nmax = (unsigned*)(denom + (long)N_NODES * 4);

    // k0: init out/denom/nmax
    k0_init<<<12500, 256, 0, stream>>>(out, denom, nmax);
    // k1: linear + scores (1024 blocks x 4 waves, grid-stride)
    k1_linear<<<1024, 256, 0, stream>>>(x, state, W, a_src, a_dst, hf, s_src, s_dst);
    // k2: segment max (1 thread / edge)
    k2_max<<<(N_EDGES + 255) / 256, 256, 0, stream>>>(ei, s_src, s_dst, nmax);
    // k3: scatter accumulate (1 wave / edge)
    {
        long threads = (long)N_EDGES * 64;
        int blocks = (int)((threads + 255) / 256);
        k3_acc<<<blocks, 256, 0, stream>>>(ei, s_src, s_dst, nmax, hf, denom, out);
    }
    // k4: finalize
    k4_fin<<<(N_NODES * 64 + 255) / 256, 256, 0, stream>>>(hf, denom, out);
}

// Round 2
// 258.258 us; speedup vs baseline: 1.6621x; 1.6621x over previous
//
#include <hip/hip_runtime.h>
#include <hip/hip_bf16.h>

#define N_NODES 50000
#define N_EDGES 800000

__device__ __forceinline__ float leaky(float l) {
    return (l >= 0.0f) ? l : 0.2f * l;
}

// ---------------- z_deg: zero in-degree counters ----------------
__global__ void z_deg(int* __restrict__ deg) {
    int i = blockIdx.x * 256 + threadIdx.x;
    if (i < N_NODES) deg[i] = 0;
}

// ---------------- k1: fused linear + attention scores ----------------
__global__ void k1_linear(const float* __restrict__ x, const float* __restrict__ state,
                          const float* __restrict__ W, const float* __restrict__ a_src,
                          const float* __restrict__ a_dst,
                          float* __restrict__ hf, float* __restrict__ s_src,
                          float* __restrict__ s_dst) {
    __shared__ float wlds[64 * 129];   // stride 129 -> conflict-free column reads
    __shared__ float asrc_l[64];
    __shared__ float adst_l[64];
    __shared__ float inrow[4][128];

    int tid = threadIdx.x;             // 256 threads = 4 waves
    for (int i = tid; i < 64 * 128; i += 256) {
        int r = i >> 7, c = i & 127;
        wlds[r * 129 + c] = W[i];
    }
    if (tid < 64) { asrc_l[tid] = a_src[tid]; adst_l[tid] = a_dst[tid]; }
    __syncthreads();

    int wave = tid >> 6;
    int lane = tid & 63;               // output dim o
    int h = lane >> 4, d = lane & 15;
    float asv = asrc_l[lane];
    float adv = adst_l[lane];
    const float* wr = &wlds[lane * 129];

    for (long n = (long)blockIdx.x * 4 + wave; n < N_NODES; n += (long)gridDim.x * 4) {
        inrow[wave][lane]      = x[n * 64 + lane];
        inrow[wave][64 + lane] = state[n * 64 + lane];
        float acc = 0.0f;
#pragma unroll 16
        for (int k = 0; k < 128; ++k)
            acc = fmaf(inrow[wave][k], wr[k], acc);
        hf[n * 64 + lane] = acc;

        float vs = acc * asv, vd = acc * adv;
#pragma unroll
        for (int off = 8; off; off >>= 1) {
            vs += __shfl_xor(vs, off);
            vd += __shfl_xor(vd, off);
        }
        if (d == 0) {
            s_src[n * 4 + h] = vs;
            s_dst[n * 4 + h] = vd;
        }
    }
}

// ---------------- k_hist: in-degree histogram ----------------
__global__ void k_hist(const int* __restrict__ ei, int* __restrict__ deg) {
    int e = blockIdx.x * 256 + threadIdx.x;
    if (e >= N_EDGES) return;
    atomicAdd(&deg[ei[N_EDGES + e]], 1);
}

// ---------------- k_scan: exclusive prefix sum over deg (1 block) ----------------
__global__ void k_scan(const int* __restrict__ deg, int* __restrict__ off,
                       int* __restrict__ pos) {
    __shared__ int wsum[16];
    __shared__ int tot;
    int tid = threadIdx.x, lane = tid & 63, wid = tid >> 6;
    int running = 0;
    for (int base = 0; base < N_NODES; base += 1024) {
        int idx = base + tid;
        int v = (idx < N_NODES) ? deg[idx] : 0;
        int inc = v;
#pragma unroll
        for (int s = 1; s < 64; s <<= 1) {
            int t = __shfl_up(inc, s);
            if (lane >= s) inc += t;
        }
        if (lane == 63) wsum[wid] = inc;
        __syncthreads();
        if (wid == 0) {
            int w = (lane < 16) ? wsum[lane] : 0;
            int wi = w;
#pragma unroll
            for (int s = 1; s < 16; s <<= 1) {
                int t = __shfl_up(wi, s);
                if (lane >= s) wi += t;
            }
            if (lane < 16) wsum[lane] = wi - w;   // exclusive wave offset
            if (lane == 15) tot = wi;             // chunk total
        }
        __syncthreads();
        int excl = running + wsum[wid] + inc - v;
        if (idx < N_NODES) { off[idx] = excl; pos[idx] = excl; }
        running += tot;
        __syncthreads();
    }
    if (tid == 0) off[N_NODES] = running;
}

// ---------------- k_scatter: bucket edges by dst ----------------
__global__ void k_scatter(const int* __restrict__ ei, int* __restrict__ pos,
                          int* __restrict__ csr_src) {
    int e = blockIdx.x * 256 + threadIdx.x;
    if (e >= N_EDGES) return;
    int dstn = ei[N_EDGES + e];
    int slot = atomicAdd(&pos[dstn], 1);
    csr_src[slot] = ei[e];
}

// ---------------- k_agg: per-dst softmax + weighted aggregation (1 wave / node) ----------------
__global__ void k_agg(const int* __restrict__ off, const int* __restrict__ csr_src,
                      const float* __restrict__ s_src, const float* __restrict__ s_dst,
                      const float* __restrict__ hf, float* __restrict__ out) {
    int wave = threadIdx.x >> 6, lane = threadIdx.x & 63;
    int n = blockIdx.x * 4 + wave;
    if (n >= N_NODES) return;
    int h = lane >> 4;                 // head for o-layout
    int b = off[n], e = off[n + 1];
    float sd  = s_dst[(long)n * 4 + h];
    float sdh = s_dst[(long)n * 4 + (lane & 3)];

    // pass 1: per-head max, 16 edges/chunk, lane = el*4 + hh
    float lmax4 = -INFINITY;
    for (int c = b; c < e; c += 16) {
        int i = c + (lane >> 2);
        if (i < e) {
            int s = csr_src[i];
            float l = leaky(s_src[(long)s * 4 + (lane & 3)] + sdh);
            lmax4 = fmaxf(lmax4, l);
        }
    }
#pragma unroll
    for (int o = 4; o < 64; o <<= 1) lmax4 = fmaxf(lmax4, __shfl_xor(lmax4, o));
    // lane j holds max for head j&3; redistribute to o-layout (head = lane>>4)
    float lmax = __shfl(lmax4, h);

    // pass 2: exp + denom + weighted sum, 64-edge chunks with coalesced src preload
    float acc = 0.0f, den = 0.0f;
    for (int c = b; c < e; c += 64) {
        int nn = min(64, e - c);
        int sv = (c + lane < e) ? csr_src[c + lane] : 0;
        for (int j = 0; j < nn; ++j) {
            int s = __shfl(sv, j);
            float l = leaky(s_src[(long)s * 4 + h] + sd);
            float ex = __expf(l - lmax);
            den += ex;
            acc = fmaf(ex, hf[(long)s * 64 + lane], acc);
        }
    }
    float v = acc / (den + 1e-12f) + hf[(long)n * 64 + lane];
    out[(long)n * 64 + lane] = (v > 0.0f) ? v : expm1f(v);
}

extern "C" void kernel_launch(void* const* d_in, const int* in_sizes, int n_in,
                              void* d_out, int out_size, void* d_ws, size_t ws_size,
                              hipStream_t stream) {
    const float* x      = (const float*)d_in[0];
    const float* state  = (const float*)d_in[1];
    const int*   ei     = (const int*)d_in[2];     // [2, E]
    // d_in[3] = edge_weight (ignored)
    const float* W      = (const float*)d_in[4];   // [64,128]
    const float* a_src  = (const float*)d_in[5];
    const float* a_dst  = (const float*)d_in[6];

    float* out = (float*)d_out;

    // ws layout: hf [N*64] f32 | s_src [N*4] | s_dst [N*4] | deg [N] i32 | off [N+1] | pos [N] | csr_src [E]
    float* hf    = (float*)d_ws;
    float* s_src = hf + (long)N_NODES * 64;
    float* s_dst = s_src + (long)N_NODES * 4;
    int*   deg   = (int*)(s_dst + (long)N_NODES * 4);
    int*   off   = deg + N_NODES;
    int*   pos   = off + N_NODES + 1;
    int*   csr   = pos + N_NODES;

    z_deg<<<(N_NODES + 255) / 256, 256, 0, stream>>>(deg);
    k1_linear<<<1024, 256, 0, stream>>>(x, state, W, a_src, a_dst, hf, s_src, s_dst);
    k_hist<<<(N_EDGES + 255) / 256, 256, 0, stream>>>(ei, deg);
    k_scan<<<1, 1024, 0, stream>>>(deg, off, pos);
    k_scatter<<<(N_EDGES + 255) / 256, 256, 0, stream>>>(ei, pos, csr);
    k_agg<<<(N_NODES + 3) / 4, 256, 0, stream>>>(off, csr, s_src, s_dst, hf, out);
}

// Round 3
// 162.684 us; speedup vs baseline: 2.6386x; 1.5875x over previous
//
#include <hip/hip_runtime.h>
#include <hip/hip_bf16.h>

#define N_NODES 50000
#define N_EDGES 800000

__device__ __forceinline__ float leaky(float l) {
    return (l >= 0.0f) ? l : 0.2f * l;
}
__device__ __forceinline__ float bf2f(unsigned short u) {
    return __uint_as_float(((unsigned)u) << 16);
}

// ---------------- k1: fused linear + attention scores ----------------
// h[n][o] = sum_k concat(x,state)[n][k] * W[o][k];  o = h*16+d
__global__ void k1_linear(const float* __restrict__ x, const float* __restrict__ state,
                          const float* __restrict__ W, const float* __restrict__ a_src,
                          const float* __restrict__ a_dst,
                          __hip_bfloat16* __restrict__ hf2, float* __restrict__ s_src4,
                          float* __restrict__ s_dst4) {
    __shared__ float wlds[64 * 132];   // pad 132: quad-bank (lane+kq)%8 -> ~2-way, free
    __shared__ float asrc_l[64];
    __shared__ float adst_l[64];
    __shared__ float inrow[4][128];

    int tid = threadIdx.x;             // 256 threads = 4 waves
    const float4* W4 = (const float4*)W;   // [64][32] quads
    for (int i = tid; i < 2048; i += 256) {
        int r = i >> 5, c = i & 31;
        *(float4*)&wlds[r * 132 + c * 4] = W4[i];
    }
    if (tid < 64) { asrc_l[tid] = a_src[tid]; adst_l[tid] = a_dst[tid]; }
    __syncthreads();

    int wave = tid >> 6;
    int lane = tid & 63;               // output dim o
    int h = lane >> 4, d = lane & 15;
    float asv = asrc_l[lane];
    float adv = adst_l[lane];
    const float* wr = &wlds[lane * 132];

    for (int n = blockIdx.x * 4 + wave; n < N_NODES; n += gridDim.x * 4) {
        inrow[wave][lane]      = x[(long)n * 64 + lane];
        inrow[wave][64 + lane] = state[(long)n * 64 + lane];
        float acc = 0.0f;
#pragma unroll
        for (int kq = 0; kq < 32; ++kq) {
            float4 wv = *(const float4*)&wr[kq * 4];
            float4 iv = *(const float4*)&inrow[wave][kq * 4];
            acc = fmaf(iv.x, wv.x, acc);
            acc = fmaf(iv.y, wv.y, acc);
            acc = fmaf(iv.z, wv.z, acc);
            acc = fmaf(iv.w, wv.w, acc);
        }
        hf2[(long)n * 64 + lane] = __float2bfloat16(acc);

        float vs = acc * asv, vd = acc * adv;
#pragma unroll
        for (int off = 8; off; off >>= 1) {
            vs += __shfl_xor(vs, off);
            vd += __shfl_xor(vd, off);
        }
        if (d == 0) {
            s_src4[(long)n * 4 + h] = vs;
            s_dst4[(long)n * 4 + h] = vd;
        }
    }
}

// ---------------- k_hist: in-degree histogram (4 edges/thread) ----------------
__global__ void k_hist(const int* __restrict__ ei, int* __restrict__ deg) {
    int t = blockIdx.x * 256 + threadIdx.x;
    if (t * 4 >= N_EDGES) return;
    int4 dv = *(const int4*)(ei + N_EDGES + t * 4);
    atomicAdd(&deg[dv.x], 1);
    atomicAdd(&deg[dv.y], 1);
    atomicAdd(&deg[dv.z], 1);
    atomicAdd(&deg[dv.w], 1);
}

// ---------------- k_assign: disjoint CSR ranges via block-scan + 1 atomic/block ----
__global__ void k_assign(const int* __restrict__ deg, int* __restrict__ off,
                         int* __restrict__ pos, int* __restrict__ ctr) {
    __shared__ int wsum[4];
    __shared__ int base_sh;
    int tid = threadIdx.x, lane = tid & 63, wid = tid >> 6;
    int i = blockIdx.x * 256 + tid;
    int v = (i < N_NODES) ? deg[i] : 0;
    int inc = v;
#pragma unroll
    for (int s = 1; s < 64; s <<= 1) {
        int t = __shfl_up(inc, s);
        if (lane >= s) inc += t;
    }
    if (lane == 63) wsum[wid] = inc;
    __syncthreads();
    if (tid == 0) {
        int s = 0;
#pragma unroll
        for (int w = 0; w < 4; ++w) { int t = wsum[w]; wsum[w] = s; s += t; }
        base_sh = atomicAdd(ctr, s);
    }
    __syncthreads();
    int excl = base_sh + wsum[wid] + inc - v;
    if (i < N_NODES) { off[i] = excl; pos[i] = excl; }
}

// ---------------- k_scatter: bucket edges by dst + precompute leaky logits ------
__global__ void k_scatter(const int* __restrict__ ei, const float* __restrict__ s_src4,
                          const float* __restrict__ s_dst4, int* __restrict__ pos,
                          int* __restrict__ csr, float* __restrict__ lg) {
    int t = blockIdx.x * 256 + threadIdx.x;
    if (t * 4 >= N_EDGES) return;
    int4 sv = *(const int4*)(ei + t * 4);
    int4 dv = *(const int4*)(ei + N_EDGES + t * 4);
    int sa[4] = {sv.x, sv.y, sv.z, sv.w};
    int da[4] = {dv.x, dv.y, dv.z, dv.w};
#pragma unroll
    for (int k = 0; k < 4; ++k) {
        int s = sa[k], dn = da[k];
        float4 ss = *(const float4*)&s_src4[(long)s * 4];
        float4 sd = *(const float4*)&s_dst4[(long)dn * 4];
        float4 l;
        l.x = leaky(ss.x + sd.x);
        l.y = leaky(ss.y + sd.y);
        l.z = leaky(ss.z + sd.z);
        l.w = leaky(ss.w + sd.w);
        int slot = atomicAdd(&pos[dn], 1);
        csr[slot] = s;
        *(float4*)&lg[(long)slot * 4] = l;
    }
}

// ---------------- k_agg: per-dst softmax + aggregation (1 wave/node, 4 edge slots)
__global__ void k_agg(const int* __restrict__ off, const int* __restrict__ deg,
                      const int* __restrict__ csr, const float* __restrict__ lg,
                      const __hip_bfloat16* __restrict__ hf2, float* __restrict__ out) {
    int wave = threadIdx.x >> 6, lane = threadIdx.x & 63;
    int n = blockIdx.x * 4 + wave;
    if (n >= N_NODES) return;
    int q = lane >> 4, d = lane & 15, hh = d >> 2;
    int b = off[n], nE = deg[n];
    long b4 = (long)b * 4;
    int nE4 = nE * 4;

    // pass 1: per-head max; flat over logit dwords, head = j&3 preserved by xor<4..32>
    float m = -INFINITY;
    for (int j = lane; j < nE4; j += 64) m = fmaxf(m, lg[b4 + j]);
    m = fmaxf(m, __shfl_xor(m, 4));
    m = fmaxf(m, __shfl_xor(m, 8));
    m = fmaxf(m, __shfl_xor(m, 16));
    m = fmaxf(m, __shfl_xor(m, 32));
    float mh = __shfl(m, hh);          // max for this lane's head

    // pass 2: 4 edges in flight (slot q), lane d owns dims 4d..4d+3 (head hh)
    float den = 0.0f, a0 = 0.0f, a1 = 0.0f, a2 = 0.0f, a3 = 0.0f;
    const unsigned short* h2 = (const unsigned short*)hf2;
    for (int c = 0; c < nE; c += 64) {
        int rem = nE - c;
        int jn = rem < 64 ? rem : 64;
        int svl = (lane < jn) ? csr[b + c + lane] : 0;
        for (int j = 0; j < jn; j += 4) {
            int myj = j + q;
            int s = __shfl(svl, myj);
            if (myj < jn) {
                float lgt = lg[b4 + (long)(c + myj) * 4 + hh];
                float ex = __expf(lgt - mh);
                den += ex;
                ushort4 hv = *(const ushort4*)&h2[(long)s * 64 + 4 * d];
                a0 = fmaf(ex, bf2f(hv.x), a0);
                a1 = fmaf(ex, bf2f(hv.y), a1);
                a2 = fmaf(ex, bf2f(hv.z), a2);
                a3 = fmaf(ex, bf2f(hv.w), a3);
            }
        }
    }
    den += __shfl_xor(den, 16); den += __shfl_xor(den, 32);
    a0 += __shfl_xor(a0, 16);   a0 += __shfl_xor(a0, 32);
    a1 += __shfl_xor(a1, 16);   a1 += __shfl_xor(a1, 32);
    a2 += __shfl_xor(a2, 16);   a2 += __shfl_xor(a2, 32);
    a3 += __shfl_xor(a3, 16);   a3 += __shfl_xor(a3, 32);

    if (q == 0) {
        ushort4 hr = *(const ushort4*)&h2[(long)n * 64 + 4 * d];
        float inv = 1.0f / (den + 1e-12f);
        float4 o;
        o.x = a0 * inv + bf2f(hr.x);
        o.y = a1 * inv + bf2f(hr.y);
        o.z = a2 * inv + bf2f(hr.z);
        o.w = a3 * inv + bf2f(hr.w);
        o.x = (o.x > 0.0f) ? o.x : expm1f(o.x);
        o.y = (o.y > 0.0f) ? o.y : expm1f(o.y);
        o.z = (o.z > 0.0f) ? o.z : expm1f(o.z);
        o.w = (o.w > 0.0f) ? o.w : expm1f(o.w);
        *(float4*)&out[(long)n * 64 + 4 * d] = o;
    }
}

extern "C" void kernel_launch(void* const* d_in, const int* in_sizes, int n_in,
                              void* d_out, int out_size, void* d_ws, size_t ws_size,
                              hipStream_t stream) {
    const float* x      = (const float*)d_in[0];
    const float* state  = (const float*)d_in[1];
    const int*   ei     = (const int*)d_in[2];     // [2, E]
    // d_in[3] = edge_weight (ignored)
    const float* W      = (const float*)d_in[4];   // [64,128]
    const float* a_src  = (const float*)d_in[5];
    const float* a_dst  = (const float*)d_in[6];

    float* out = (float*)d_out;

    // ws layout: lg [E*4] f32 | s_src4 [N*4] | s_dst4 [N*4] | hf2 [N*64] bf16 |
    //            deg [N] | off [N] | pos [N] | ctr [4 ints] | csr [E]
    float* lg     = (float*)d_ws;
    float* s_src4 = lg + (long)N_EDGES * 4;
    float* s_dst4 = s_src4 + (long)N_NODES * 4;
    __hip_bfloat16* hf2 = (__hip_bfloat16*)(s_dst4 + (long)N_NODES * 4);
    int*   deg    = (int*)(hf2 + (long)N_NODES * 64);
    int*   off    = deg + N_NODES;
    int*   pos    = off + N_NODES;
    int*   ctr    = pos + N_NODES;
    int*   csr    = ctr + 4;

    hipMemsetAsync(deg, 0, N_NODES * sizeof(int), stream);
    hipMemsetAsync(ctr, 0, sizeof(int), stream);
    k1_linear<<<2048, 256, 0, stream>>>(x, state, W, a_src, a_dst, hf2, s_src4, s_dst4);
    k_hist<<<(N_EDGES / 4 + 255) / 256, 256, 0, stream>>>(ei, deg);
    k_assign<<<(N_NODES + 255) / 256, 256, 0, stream>>>(deg, off, pos, ctr);
    k_scatter<<<(N_EDGES / 4 + 255) / 256, 256, 0, stream>>>(ei, s_src4, s_dst4, pos, csr, lg);
    k_agg<<<(N_NODES + 3) / 4, 256, 0, stream>>>(off, deg, csr, lg, hf2, out);
}